// Round 1
// baseline (249.945 us; speedup 1.0000x reference)
//
#include <hip/hip_runtime.h>

// y[rows[k]] += vals[k] * x[cols[k]]  — M=N=262144, NNZ=8388608, out 512x512 f32.
// Pipeline: init cursors -> direct LDS bucket scatter (1 atomic/entry) into 32
// row-bins -> per-bin-slice LDS accumulation (512 thr, 100% occ) -> reduction.

#define BINS         32
#define ROW_SHIFT    13            // 8192 rows per bin
#define ROWS_PER_BIN 8192
#define ENT          2048          // entries per scatter block (8/thread)
#define BKT_CAP      112           // LDS bucket capacity: mean 64, sigma 7.9 -> 6 sigma
#define KST          114           // key bucket stride (u16), padded to rotate banks
#define VST          113           // val bucket stride (f32), padded to rotate banks
#define CUR_STRIDE   32            // global cursor padding: 1 counter per 128B line
#define OVF_SLOT     (BINS * CUR_STRIDE)
#define OVF_CAP      65536

typedef int   __attribute__((ext_vector_type(4))) i32x4;
typedef float __attribute__((ext_vector_type(4))) f32x4;

// ---------------- fallback path (known-correct) ----------------

__global__ __launch_bounds__(256) void zero_out_kernel(float* __restrict__ y, int n) {
    int i = blockIdx.x * blockDim.x + threadIdx.x;
    if (i < n) y[i] = 0.0f;
}

__global__ __launch_bounds__(256) void spmv_coo_scatter(
    const float* __restrict__ vals, const int* __restrict__ rows,
    const int* __restrict__ cols, const float* __restrict__ x,
    float* __restrict__ y, int nnz)
{
    int i = (blockIdx.x * blockDim.x + threadIdx.x) * 4;
    if (i + 3 < nnz) {
        float4 v = *reinterpret_cast<const float4*>(vals + i);
        int4   r = *reinterpret_cast<const int4*>(rows + i);
        int4   c = *reinterpret_cast<const int4*>(cols + i);
        atomicAdd(&y[r.x], v.x * x[c.x]);
        atomicAdd(&y[r.y], v.y * x[c.y]);
        atomicAdd(&y[r.z], v.z * x[c.z]);
        atomicAdd(&y[r.w], v.w * x[c.w]);
    } else {
        for (; i < nnz; ++i) atomicAdd(&y[rows[i]], vals[i] * x[cols[i]]);
    }
}

// ---------------- binned path ----------------

__global__ __launch_bounds__(256) void init_cursors(unsigned* __restrict__ gcur, int n) {
    int i = blockIdx.x * 256 + threadIdx.x;
    if (i < n) gcur[i] = 0u;
}

// Direct LDS bucket scatter: single atomic cursor bump per entry, then per-wave
// coalesced copy-out of each bucket into its bin's global region.
__global__ __launch_bounds__(256) void scatter_bucket_kernel(
    const int*   __restrict__ rows, const int* __restrict__ cols,
    const float* __restrict__ vals, const float* __restrict__ x, int nnz,
    unsigned* __restrict__ gcur, unsigned cap,
    unsigned short* __restrict__ okeys, float* __restrict__ ocontrib,
    uint2* __restrict__ ovf)
{
    __shared__ unsigned short skey[BINS * KST];   //  7296 B
    __shared__ float          sval[BINS * VST];   // 14464 B
    __shared__ unsigned cur[BINS];
    __shared__ unsigned scnt[BINS];
    __shared__ unsigned resv[BINS];

    const int t = threadIdx.x;
    if (t < BINS) cur[t] = 0u;
    __syncthreads();

    const int seg = blockIdx.x * ENT;

    int   rr[8];
    float ff[8];

    // Load triplets (non-temporal: don't evict x from L2), compute contribs.
    #pragma unroll
    for (int ch = 0; ch < 2; ++ch) {
        int base = seg + ch * 1024 + t * 4;
        if (base + 3 < nnz) {
            i32x4 r4 = __builtin_nontemporal_load(reinterpret_cast<const i32x4*>(rows + base));
            i32x4 c4 = __builtin_nontemporal_load(reinterpret_cast<const i32x4*>(cols + base));
            f32x4 v4 = __builtin_nontemporal_load(reinterpret_cast<const f32x4*>(vals + base));
            rr[ch*4+0] = r4.x; ff[ch*4+0] = v4.x * x[c4.x];
            rr[ch*4+1] = r4.y; ff[ch*4+1] = v4.y * x[c4.y];
            rr[ch*4+2] = r4.z; ff[ch*4+2] = v4.z * x[c4.z];
            rr[ch*4+3] = r4.w; ff[ch*4+3] = v4.w * x[c4.w];
        } else {
            #pragma unroll
            for (int j = 0; j < 4; ++j) {
                int idx = base + j;
                if (idx < nnz) { rr[ch*4+j] = rows[idx]; ff[ch*4+j] = vals[idx] * x[cols[idx]]; }
                else           { rr[ch*4+j] = -1; ff[ch*4+j] = 0.0f; }
            }
        }
    }

    // Place: one LDS atomic per entry; rare overflow spills to global list.
    #pragma unroll
    for (int j = 0; j < 8; ++j) {
        if (rr[j] >= 0) {
            int b = rr[j] >> ROW_SHIFT;
            unsigned p = atomicAdd(&cur[b], 1u);
            if (p < BKT_CAP) {
                skey[b * KST + p] = (unsigned short)(rr[j] & (ROWS_PER_BIN - 1));
                sval[b * VST + p] = ff[j];
            } else {
                unsigned q = atomicAdd(&gcur[OVF_SLOT], 1u);
                if (q < OVF_CAP) ovf[q] = make_uint2((unsigned)rr[j], __float_as_uint(ff[j]));
            }
        }
    }
    __syncthreads();

    // Reserve global space per bin (padded cursors: 32 independent cache lines).
    if (t < BINS) {
        unsigned c = cur[t]; if (c > BKT_CAP) c = BKT_CAP;
        scnt[t] = c;
        resv[t] = atomicAdd(&gcur[t * CUR_STRIDE], c);
    }
    __syncthreads();

    // Copy-out: wave w owns buckets [8w, 8w+8); coalesced within each bucket run.
    const int wave = t >> 6, lane = t & 63;
    #pragma unroll
    for (int k = 0; k < BINS / 4; ++k) {
        int b = wave * (BINS / 4) + k;
        unsigned cnt  = scnt[b];
        unsigned base = resv[b];
        const size_t binoff = (size_t)b * cap;
        for (unsigned i = lane; i < cnt; i += 64) {
            unsigned off = base + i;
            if (off < cap) {
                okeys[binoff + off]    = skey[b * KST + i];
                ocontrib[binoff + off] = sval[b * VST + i];
            }
        }
    }
}

// One block per (bin, slice): accumulate slice entries into LDS acc, dump partials.
// 512 threads x 32KB LDS -> 4 blocks/CU = 32 waves/CU (100% occupancy).
__global__ __launch_bounds__(512) void accum2_kernel(
    const unsigned short* __restrict__ okeys, const float* __restrict__ ocontrib,
    const unsigned* __restrict__ gcur, unsigned cap,
    const uint2* __restrict__ ovf,
    float* __restrict__ partials, int slices)
{
    __shared__ float acc[ROWS_PER_BIN];
    const int t   = threadIdx.x;
    const int bin = blockIdx.x / slices;
    const int sl  = blockIdx.x - bin * slices;

    float4 z = make_float4(0.f, 0.f, 0.f, 0.f);
    #pragma unroll
    for (int i = 0; i < ROWS_PER_BIN / (512 * 4); ++i)
        *reinterpret_cast<float4*>(&acc[(i * 512 + t) * 4]) = z;
    __syncthreads();

    unsigned count = gcur[bin * CUR_STRIDE];
    if (count > cap) count = cap;
    unsigned chunk = ((count + (unsigned)slices - 1u) / (unsigned)slices + 3u) & ~3u;
    unsigned lo = (unsigned)sl * chunk;
    unsigned hi = lo + chunk; if (hi > count) hi = count;

    const unsigned short* k = okeys    + (size_t)bin * cap;
    const float*          c = ocontrib + (size_t)bin * cap;

    unsigned i = lo + (unsigned)t * 4u;
    for (; i + 3u < hi; i += 2048u) {
        ushort4 k4 = *reinterpret_cast<const ushort4*>(k + i);
        float4  c4 = *reinterpret_cast<const float4*>(c + i);
        atomicAdd(&acc[k4.x], c4.x);
        atomicAdd(&acc[k4.y], c4.y);
        atomicAdd(&acc[k4.z], c4.z);
        atomicAdd(&acc[k4.w], c4.w);
    }
    for (; i < hi; ++i) atomicAdd(&acc[k[i]], c[i]);

    // Overflow entries (expected count: 0) folded in by slice 0 of each bin.
    if (sl == 0) {
        unsigned ovn = gcur[OVF_SLOT];
        if (ovn > OVF_CAP) ovn = OVF_CAP;
        for (unsigned j = (unsigned)t; j < ovn; j += 512u) {
            uint2 e = ovf[j];
            if ((int)(e.x >> ROW_SHIFT) == bin)
                atomicAdd(&acc[e.x & (ROWS_PER_BIN - 1)], __uint_as_float(e.y));
        }
    }
    __syncthreads();

    float* p = partials + (size_t)blockIdx.x * ROWS_PER_BIN;
    #pragma unroll
    for (int i2 = 0; i2 < ROWS_PER_BIN / (512 * 4); ++i2) {
        int l = (i2 * 512 + t) * 4;
        *reinterpret_cast<float4*>(p + l) = *reinterpret_cast<const float4*>(&acc[l]);
    }
}

// Sum the slice partials per row, 4 rows per thread (float4).
__global__ __launch_bounds__(256) void reduce2_kernel(
    const float* __restrict__ partials, float* __restrict__ y, int out_size, int slices)
{
    int r0 = (blockIdx.x * 256 + threadIdx.x) * 4;
    if (r0 >= out_size) return;
    if (r0 + 3 < out_size) {
        int bin = r0 >> ROW_SHIFT, local = r0 & (ROWS_PER_BIN - 1);
        const float* p = partials + ((size_t)bin * slices) * ROWS_PER_BIN + local;
        float4 s = make_float4(0.f, 0.f, 0.f, 0.f);
        for (int j = 0; j < slices; ++j) {
            float4 v = *reinterpret_cast<const float4*>(p + (size_t)j * ROWS_PER_BIN);
            s.x += v.x; s.y += v.y; s.z += v.z; s.w += v.w;
        }
        *reinterpret_cast<float4*>(y + r0) = s;
    } else {
        for (int r = r0; r < out_size; ++r) {
            int bin = r >> ROW_SHIFT, local = r & (ROWS_PER_BIN - 1);
            const float* p = partials + ((size_t)bin * slices) * ROWS_PER_BIN + local;
            float s = 0.f;
            for (int j = 0; j < slices; ++j) s += p[(size_t)j * ROWS_PER_BIN];
            y[r] = s;
        }
    }
}

extern "C" void kernel_launch(void* const* d_in, const int* in_sizes, int n_in,
                              void* d_out, int out_size, void* d_ws, size_t ws_size,
                              hipStream_t stream) {
    const float* x    = (const float*)d_in[0];
    const float* vals = (const float*)d_in[1];
    const int*   rows = (const int*)d_in[2];
    const int*   cols = (const int*)d_in[3];
    float* y = (float*)d_out;

    const int nnz  = in_sizes[1];
    const int bins = (out_size + ROWS_PER_BIN - 1) / ROWS_PER_BIN;

    unsigned cap = (unsigned)(nnz / (bins > 0 ? bins : 1)) + 16384u;   // ~5.7 sigma slack
    cap = (cap + 3u) & ~3u;

    auto align256 = [](size_t v) { return (v + 255) & ~(size_t)255; };

    int slices = 32;
    size_t off_contrib = 0, off_keys = 0, off_partials = 0, off_gcur = 0, off_ovf = 0, need = 0;
    for (int attempt = 0; attempt < 2; ++attempt) {
        off_contrib  = 0;
        off_keys     = align256(off_contrib + (size_t)BINS * cap * 4);
        off_partials = align256(off_keys + (size_t)BINS * cap * 2);
        off_gcur     = align256(off_partials + (size_t)BINS * slices * ROWS_PER_BIN * 4);
        off_ovf      = align256(off_gcur + (size_t)(OVF_SLOT + CUR_STRIDE) * 4);
        need         = align256(off_ovf + (size_t)OVF_CAP * 8);
        if (need <= ws_size) break;
        slices = 16;                       // shrink partials if workspace is tight
    }

    const bool ok = (bins == BINS) && (need <= ws_size) && (nnz > 0) && (out_size % 4 == 0);

    if (!ok) {
        zero_out_kernel<<<(out_size + 255) / 256, 256, 0, stream>>>(y, out_size);
        spmv_coo_scatter<<<(nnz + 1023) / 1024, 256, 0, stream>>>(vals, rows, cols, x, y, nnz);
        return;
    }

    char* w = (char*)d_ws;
    float*          ocontrib = (float*)(w + off_contrib);
    unsigned short* okeys    = (unsigned short*)(w + off_keys);
    float*          partials = (float*)(w + off_partials);
    unsigned*       gcur     = (unsigned*)(w + off_gcur);
    uint2*          ovf      = (uint2*)(w + off_ovf);

    const int ncur = OVF_SLOT + 1;
    init_cursors<<<(ncur + 255) / 256, 256, 0, stream>>>(gcur, ncur);
    scatter_bucket_kernel<<<(nnz + ENT - 1) / ENT, 256, 0, stream>>>(
        rows, cols, vals, x, nnz, gcur, cap, okeys, ocontrib, ovf);
    accum2_kernel<<<BINS * slices, 512, 0, stream>>>(
        okeys, ocontrib, gcur, cap, ovf, partials, slices);
    reduce2_kernel<<<(out_size / 4 + 255) / 256, 256, 0, stream>>>(
        partials, y, out_size, slices);
}